// Round 3
// baseline (391.356 us; speedup 1.0000x reference)
//
#include <hip/hip_runtime.h>
#include <stdint.h>

// TernaryLinear: C[8192,4096] = x[8192,4096] @ W[4096,4096]^T + b
// i8 path: W is exactly {-1,0,+1} -> int8 exact; x quantized per-row absmax.
#define M_DIM 8192
#define N_DIM 4096
#define K_DIM 4096

// ---- 256x256 i8 GEMM, 32x32x32 MFMA, 4 balanced phases/tile ----
#define BM 256
#define BN 256
#define BK 128                    // i8 K elems per tile = 128 B per row
#define NT (K_DIM / BK)           // 32 k-tiles
#define NBX (N_DIM / BN)          // 16
#define NWG ((M_DIM / BM) * NBX)  // 32*16 = 512 blocks

typedef int intx4  __attribute__((ext_vector_type(4)));
typedef int intx16 __attribute__((ext_vector_type(16)));

typedef __attribute__((address_space(1))) void gv_t;
typedef __attribute__((address_space(3))) void lv_t;

// async global->LDS, 16B per lane. LDS dest is wave-uniform base + lane*16.
__device__ __forceinline__ void gl2lds16(const void* g, void* l) {
    __builtin_amdgcn_global_load_lds((const gv_t*)g, (lv_t*)l, 16, 0, 0);
}

__device__ __forceinline__ void blockbar() {
    asm volatile("" ::: "memory");
    __builtin_amdgcn_s_barrier();
    asm volatile("" ::: "memory");
}

__device__ __forceinline__ int pack4_scaled(float4 v, float s) {
    int a = __float2int_rn(v.x * s) & 255;
    int b = __float2int_rn(v.y * s) & 255;
    int c = __float2int_rn(v.z * s) & 255;
    int d = __float2int_rn(v.w * s) & 255;
    return a | (b << 8) | (c << 16) | (d << 24);
}

// x fp32 -> i8 with per-row absmax scale. One block per row; 256 thr x 16 elem.
// Lane-contiguous float4 loads (stride 256) + coalesced int stores.
__global__ __launch_bounds__(256) void quant_x_i8(
    const float* __restrict__ x, signed char* __restrict__ q,
    float* __restrict__ dq) {
    const int row = blockIdx.x;
    const int tid = threadIdx.x;
    const float4* p = (const float4*)(x + (size_t)row * K_DIM);
    float4 v0 = p[tid], v1 = p[tid + 256], v2 = p[tid + 512], v3 = p[tid + 768];
    float m = fmaxf(fmaxf(fabsf(v0.x), fabsf(v0.y)), fmaxf(fabsf(v0.z), fabsf(v0.w)));
    m = fmaxf(m, fmaxf(fmaxf(fabsf(v1.x), fabsf(v1.y)), fmaxf(fabsf(v1.z), fabsf(v1.w))));
    m = fmaxf(m, fmaxf(fmaxf(fabsf(v2.x), fabsf(v2.y)), fmaxf(fabsf(v2.z), fabsf(v2.w))));
    m = fmaxf(m, fmaxf(fmaxf(fabsf(v3.x), fabsf(v3.y)), fmaxf(fabsf(v3.z), fabsf(v3.w))));
#pragma unroll
    for (int off = 32; off >= 1; off >>= 1)
        m = fmaxf(m, __shfl_xor(m, off, 64));
    __shared__ float wmax[4];
    if ((tid & 63) == 0) wmax[tid >> 6] = m;
    __syncthreads();
    const float rm = fmaxf(fmaxf(wmax[0], wmax[1]), fmaxf(wmax[2], wmax[3]));
    const float s = rm > 0.f ? 127.f / rm : 0.f;
    if (tid == 0) dq[row] = rm * (1.f / 127.f);
    int* qo = (int*)(q + (size_t)row * K_DIM);
    qo[tid]       = pack4_scaled(v0, s);
    qo[tid + 256] = pack4_scaled(v1, s);
    qo[tid + 512] = pack4_scaled(v2, s);
    qo[tid + 768] = pack4_scaled(v3, s);
}

// W fp32 (exactly -1/0/+1) -> i8. 16 elems per thread, lane-contiguous.
__global__ __launch_bounds__(256) void quant_w_i8(
    const float* __restrict__ w, signed char* __restrict__ q) {
    const size_t base = (size_t)blockIdx.x * 1024 + threadIdx.x;
    const float4* p = (const float4*)w;
    int* qo = (int*)q;
    qo[base]       = pack4_scaled(p[base], 1.f);
    qo[base + 256] = pack4_scaled(p[base + 256], 1.f);
    qo[base + 512] = pack4_scaled(p[base + 512], 1.f);
    qo[base + 768] = pack4_scaled(p[base + 768], 1.f);
}

// 256x256 i8 GEMM with mfma_i32_32x32x32_i8, 4 phases/tile x 8 MFMA each.
// T1 XCD swizzle, T2 LDS XOR-swizzle, T4 counted vmcnt(4)/tile, T5 setprio.
// 8 waves (2Mx4N), each wave 128x64 output via 4x2 frags of 32x32.
// LDS 128 KiB: A [2buf][2 rh][128 rows][8 slots][16B] @0, B same @65536.
// Stage rotation per tile t: P1 stA(obuf,rh0,t+1), P2 stA(obuf,rh1,t+1),
// P3 stB(buf,rh0,t+2), P4 stB(buf,rh1,t+2); vmcnt(4) at tile end.
__global__ __launch_bounds__(512, 2) void gemm_bt_i8_32x32(
    const signed char* __restrict__ A,   // M x K i8
    const signed char* __restrict__ B,   // N x K i8
    const float* __restrict__ dq,        // M per-row dequant scale
    const float* __restrict__ bias,      // N
    float* __restrict__ C) {             // M x N fp32
    __shared__ signed char lds[131072];

    const int tid  = threadIdx.x;
    const int lane = tid & 63;
    const int wv   = tid >> 6;   // 0..7
    const int wm   = wv >> 2;    // 0..1 (M half)
    const int wn   = wv & 3;     // 0..3 (N quarter)

    // T1: bijective XCD-aware block swizzle (NWG % 8 == 0)
    const int bid = blockIdx.x;
    const int swz = (bid & 7) * (NWG / 8) + (bid >> 3);
    const int row0 = (swz / NBX) * BM;
    const int col0 = (swz % NBX) * BN;

    // ---- staging geometry: linear LDS dest + inverse-swizzled global src ----
    const int l8   = lane >> 3;                   // row-within-8
    const int slot = ((lane & 7) ^ l8) << 4;      // pre-swizzled source byte col
    const int prow = wv * 8 + l8;                 // region row (sweep 0)
    const int ldst = wv * 1024 + lane * 16;       // linear LDS dest in region

    const signed char* gA = A + (size_t)(row0 + prow) * K_DIM + slot;
    const signed char* gB = B + (size_t)(col0 + prow) * K_DIM + slot;

    auto stA = [&](int buf, int rh, int kt) {
        const signed char* g = gA + (size_t)rh * (128 * K_DIM) + kt * BK;
        signed char* l = &lds[buf * 32768 + rh * 16384 + ldst];
        gl2lds16(g, l);
        gl2lds16(g + (size_t)64 * K_DIM, l + 8192);
    };
    auto stB = [&](int buf, int rh, int kt) {
        const signed char* g = gB + (size_t)rh * (128 * K_DIM) + kt * BK;
        signed char* l = &lds[65536 + buf * 32768 + rh * 16384 + ldst];
        gl2lds16(g, l);
        gl2lds16(g + (size_t)64 * K_DIM, l + 8192);
    };

    // ---- fragment read geometry (T2 swizzled) ----
    // 32x32x32 frag: row = lane&31, 16B k-chunk = lane>>5 (K=32 per step).
    // abs chunk for kstep ks = ks*2 + (lane>>5); swizzled slot = chunk ^ (lane&7).
    const int l5 = lane & 31;
    const int hk = lane >> 5;
    const int lx = lane & 7;
    const int sw[4] = { (((0 * 2 + hk) ^ lx) << 4), (((1 * 2 + hk) ^ lx) << 4),
                        (((2 * 2 + hk) ^ lx) << 4), (((3 * 2 + hk) ^ lx) << 4) };
    const int aRowB = wm * 16384 + l5 * 128;                       // +i*4096
    const int bRowB = 65536 + (wn >> 1) * 16384 + ((wn & 1) * 64 + l5) * 128;  // +j*4096

#define LDA(bb, i, ks) (*(const intx4*)&lds[(bb) * 32768 + aRowB + (i) * 4096 + sw[ks]])
#define LDB(bb, j, ks) (*(const intx4*)&lds[(bb) * 32768 + bRowB + (j) * 4096 + sw[ks]])

    intx16 acc[4][2];
#pragma unroll
    for (int i = 0; i < 4; ++i) {
        acc[i][0] = (intx16)0;
        acc[i][1] = (intx16)0;
    }

    intx4 aE[4], aO[4], bk0[2], bk1[2], bk2[2], bk3[2];

    // ---- prologue: tile0 A+B into buf0, tile1 B into buf1 (12 loads) ----
    stA(0, 0, 0); stA(0, 1, 0); stB(0, 0, 0); stB(0, 1, 0);
    stB(1, 0, 1); stB(1, 1, 1);
    asm volatile("s_waitcnt vmcnt(4)" ::: "memory");  // tile0 fully landed
    blockbar();

#define KT(x) ((x) < NT ? (x) : (NT - 1))

#define MFMA8(av, bv)                                                          \
    _Pragma("unroll") for (int i = 0; i < 4; ++i) {                            \
        acc[i][0] = __builtin_amdgcn_mfma_i32_32x32x32_i8(av[i], bv[0], acc[i][0], 0, 0, 0); \
        acc[i][1] = __builtin_amdgcn_mfma_i32_32x32x32_i8(av[i], bv[1], acc[i][1], 0, 0, 0); \
    }

// Region read-completion vs overwrite-issue windows (all verified):
//   buf.A reads: A is read same-phase (aE/aO per phase); each phase's reads
//   complete at its lgkm(0) before the closing barrier; stA targets OBUF
//   (depth-1), whose reads finished last tile. OK
//   buf.B reads: all 8 issued P1+P2, complete by P2 lgkm(0) -> stB(buf) at
//   P3/P4 is after P2's closing barrier. OK
//   vmcnt(4) at tile end: drains this tile's P1/P2 stA (next tile's A) and
//   everything older (next tile's B staged last tile); P3/P4 stB (t+2) fly.
#define TILE(t, b, o)                                                          \
  {                                                                            \
    /* P1: B ks0,ks1 + A ks0; stage A(o,rh0,t+1) */                            \
    bk0[0] = LDB(b, 0, 0); bk0[1] = LDB(b, 1, 0);                              \
    bk1[0] = LDB(b, 0, 1); bk1[1] = LDB(b, 1, 1);                              \
    aE[0] = LDA(b, 0, 0); aE[1] = LDA(b, 1, 0);                                \
    aE[2] = LDA(b, 2, 0); aE[3] = LDA(b, 3, 0);                                \
    stA(o, 0, KT((t) + 1));                                                    \
    blockbar();                                                                \
    asm volatile("s_waitcnt lgkmcnt(0)" ::: "memory");                         \
    __builtin_amdgcn_sched_barrier(0);                                         \
    __builtin_amdgcn_s_setprio(1);                                             \
    MFMA8(aE, bk0);                                                            \
    __builtin_amdgcn_s_setprio(0);                                             \
    blockbar();                                                                \
    /* P2: B ks2,ks3 + A ks1; stage A(o,rh1,t+1) */                            \
    bk2[0] = LDB(b, 0, 2); bk2[1] = LDB(b, 1, 2);                              \
    bk3[0] = LDB(b, 0, 3); bk3[1] = LDB(b, 1, 3);                              \
    aO[0] = LDA(b, 0, 1); aO[1] = LDA(b, 1, 1);                                \
    aO[2] = LDA(b, 2, 1); aO[3] = LDA(b, 3, 1);                                \
    stA(o, 1, KT((t) + 1));                                                    \
    blockbar();                                                                \
    asm volatile("s_waitcnt lgkmcnt(0)" ::: "memory");                         \
    __builtin_amdgcn_sched_barrier(0);                                         \
    __builtin_amdgcn_s_setprio(1);                                             \
    MFMA8(aO, bk1);                                                            \
    __builtin_amdgcn_s_setprio(0);                                             \
    blockbar();                                                                \
    /* P3: A ks2; stage B(b,rh0,t+2) */                                        \
    aE[0] = LDA(b, 0, 2); aE[1] = LDA(b, 1, 2);                                \
    aE[2] = LDA(b, 2, 2); aE[3] = LDA(b, 3, 2);                                \
    stB(b, 0, KT((t) + 2));                                                    \
    blockbar();                                                                \
    asm volatile("s_waitcnt lgkmcnt(0)" ::: "memory");                         \
    __builtin_amdgcn_sched_barrier(0);                                         \
    __builtin_amdgcn_s_setprio(1);                                             \
    MFMA8(aE, bk2);                                                            \
    __builtin_amdgcn_s_setprio(0);                                             \
    blockbar();                                                                \
    /* P4: A ks3; stage B(b,rh1,t+2); counted vmcnt (never 0) */               \
    aO[0] = LDA(b, 0, 3); aO[1] = LDA(b, 1, 3);                                \
    aO[2] = LDA(b, 2, 3); aO[3] = LDA(b, 3, 3);                                \
    stB(b, 1, KT((t) + 2));                                                    \
    blockbar();                                                                \
    asm volatile("s_waitcnt lgkmcnt(0)" ::: "memory");                         \
    __builtin_amdgcn_sched_barrier(0);                                         \
    __builtin_amdgcn_s_setprio(1);                                             \
    MFMA8(aO, bk3);                                                            \
    __builtin_amdgcn_s_setprio(0);                                             \
    asm volatile("s_waitcnt vmcnt(4)" ::: "memory");                           \
    blockbar();                                                                \
  }

    for (int t = 0; t < NT; t += 2) {
        TILE(t, 0, 1)
        TILE(t + 1, 1, 0)
    }
#undef TILE
#undef KT
#undef MFMA8
#undef LDA
#undef LDB

    // Drain outstanding global_load_lds before the block can retire (LDS
    // DMA landing after LDS reallocation would corrupt another block).
    asm volatile("s_waitcnt vmcnt(0)" ::: "memory");

    // epilogue: 32x32 C/D layout: col=lane&31, row=(r&3)+8*(r>>2)+4*(lane>>5)
    const int ccol = col0 + wn * 64 + l5;
    const int hk4  = hk * 4;
#pragma unroll
    for (int j = 0; j < 2; ++j) {
        const float bv = bias[ccol + j * 32];
#pragma unroll
        for (int i = 0; i < 4; ++i) {
            const int rbase = row0 + wm * 128 + i * 32 + hk4;
#pragma unroll
            for (int r = 0; r < 16; ++r) {
                const int grow = rbase + (r & 3) + 8 * (r >> 2);
                C[(size_t)grow * N_DIM + ccol + j * 32] =
                    (float)acc[i][j][r] * dq[grow] + bv;
            }
        }
    }
}

// Correctness fallback if workspace is too small.
__global__ __launch_bounds__(256) void naive_ternary(
    const float* __restrict__ x, const float* __restrict__ w,
    const float* __restrict__ bias, float* __restrict__ out) {
    const int col = blockIdx.x * 64 + (threadIdx.x & 63);
    const int row = blockIdx.y * 4 + (threadIdx.x >> 6);
    const float* xr = x + (size_t)row * K_DIM;
    const float* wr = w + (size_t)col * K_DIM;
    float s = 0.f;
    for (int k = 0; k < K_DIM; ++k) s += xr[k] * wr[k];
    out[(size_t)row * N_DIM + col] = s + bias[col];
}

extern "C" void kernel_launch(void* const* d_in, const int* in_sizes, int n_in,
                              void* d_out, int out_size, void* d_ws, size_t ws_size,
                              hipStream_t stream) {
    const float* x    = (const float*)d_in[0];
    const float* w    = (const float*)d_in[1];
    const float* bias = (const float*)d_in[2];
    float* out = (float*)d_out;

    const size_t xN = (size_t)M_DIM * K_DIM;   // 33.55M
    const size_t wN = (size_t)N_DIM * K_DIM;   // 16.78M
    const size_t need = xN + wN + (size_t)M_DIM * sizeof(float);  // ~50.4 MB

    if (ws_size >= need) {
        signed char* xq = (signed char*)d_ws;
        signed char* wq = xq + xN;
        float* dq = (float*)(wq + wN);
        quant_x_i8<<<M_DIM, 256, 0, stream>>>(x, xq, dq);
        quant_w_i8<<<(int)(wN / 16 / 256), 256, 0, stream>>>(w, wq);
        gemm_bt_i8_32x32<<<NWG, 512, 0, stream>>>(xq, wq, dq, bias, out);
    } else {
        dim3 grid(N_DIM / 64, M_DIM / 4);
        naive_ternary<<<grid, 256, 0, stream>>>(x, w, bias, out);
    }
}